// Round 16
// baseline (486.202 us; speedup 1.0000x reference)
//
#include <hip/hip_runtime.h>
#include <hip/hip_fp16.h>

typedef _Float16 f16;
typedef _Float16 half8 __attribute__((ext_vector_type(8)));
typedef _Float16 half4v __attribute__((ext_vector_type(4)));
typedef _Float16 half2v __attribute__((ext_vector_type(2)));
typedef float f32x4 __attribute__((ext_vector_type(4)));

#define AS1(p) ((const __attribute__((address_space(1))) void*)(p))
#define AS3(p) ((__attribute__((address_space(3))) void*)(p))

__device__ __forceinline__ void gload_lds16(const void* g, void* l) {
    __builtin_amdgcn_global_load_lds(AS1(g), AS3(l), 16, 0, 0);
}

// ---------------------------------------------------------------------------
// Fused input conversions: x, in_proj_w, out_proj_w (f32->f16) and
// x_proj_w (33x2048 -> zero-padded 48x2048 f16).  Grid 3456.
// ---------------------------------------------------------------------------
__global__ __launch_bounds__(256)
void prep_k(const float* __restrict__ x, const float* __restrict__ w_in,
            const float* __restrict__ w_xp, const float* __restrict__ w_out,
            f16* __restrict__ xh, f16* __restrict__ wih,
            f16* __restrict__ Wh, f16* __restrict__ woh) {
    int b = blockIdx.x;
    if (b < 2048) {
        for (int i = b * 256 + threadIdx.x; i < 4194304; i += 2048 * 256) {
            float4 v = ((const float4*)x)[i];
            half4v o; o[0] = (f16)v.x; o[1] = (f16)v.y; o[2] = (f16)v.z; o[3] = (f16)v.w;
            ((half4v*)xh)[i] = o;
        }
    } else if (b < 2560) {
        for (int i = (b - 2048) * 256 + threadIdx.x; i < 1048576; i += 512 * 256) {
            float4 v = ((const float4*)w_in)[i];
            half4v o; o[0] = (f16)v.x; o[1] = (f16)v.y; o[2] = (f16)v.z; o[3] = (f16)v.w;
            ((half4v*)wih)[i] = o;
        }
    } else if (b < 2944) {
        int idx = (b - 2560) * 256 + threadIdx.x;   // 0..98303
        int e = idx >> 11;
        int k = idx & 2047;
        Wh[idx] = (e < 33) ? (f16)w_xp[e * 2048 + k] : (f16)0.f;
    } else {
        for (int i = (b - 2944) * 256 + threadIdx.x; i < 524288; i += 512 * 256) {
            float4 v = ((const float4*)w_out)[i];
            half4v o; o[0] = (f16)v.x; o[1] = (f16)v.y; o[2] = (f16)v.z; o[3] = (f16)v.w;
            ((half4v*)woh)[i] = o;
        }
    }
}

// ===========================================================================
// Persistent 256x256 8-phase GEMM (proven variant), f16 MFMA 16x16x32.
// NFAST=false: 4x8 supertile (GEMM1).  NFAST=true: bn-fastest (GEMM2).
// Bridged prologue + vmcnt(6) pipeline.
// ===========================================================================
__device__ __forceinline__ void stage_q(const f16* __restrict__ g, int ld,
                                        int row0, int gk, f16* q,
                                        int tid, int wave) {
#pragma unroll
    for (int rd = 0; rd < 2; ++rd) {
        int t = rd * 512 + tid;
        int r = t >> 2;                       // row 0..255
        int cu = (t & 3) ^ ((r >> 1) & 3);    // unswizzled chunk for this slot
        gload_lds16(g + (size_t)(row0 + r) * ld + gk + cu * 8,
                    q + rd * 4096 + wave * 512);   // wave-uniform linear dest
    }
}

#define PH(Q, KH, MH, LOADB, STAGE, WAITC)                                    \
  {                                                                           \
    half8 afr[4];                                                             \
    {                                                                         \
      const f16* aq = &lds[Q][0][KH][0];                                      \
      int ra = wm * 128 + (MH) * 64 + lr;                                     \
      afr[0] = *(const half8*)(aq + (ra +  0) * 32 + cofs);                   \
      afr[1] = *(const half8*)(aq + (ra + 16) * 32 + cofs);                   \
      afr[2] = *(const half8*)(aq + (ra + 32) * 32 + cofs);                   \
      afr[3] = *(const half8*)(aq + (ra + 48) * 32 + cofs);                   \
    }                                                                         \
    if (LOADB) {                                                              \
      const f16* bq = &lds[Q][1][KH][0];                                      \
      int rb = wn * 64 + lr;                                                  \
      bfr[0] = *(const half8*)(bq + (rb +  0) * 32 + cofs);                   \
      bfr[1] = *(const half8*)(bq + (rb + 16) * 32 + cofs);                   \
      bfr[2] = *(const half8*)(bq + (rb + 32) * 32 + cofs);                   \
      bfr[3] = *(const half8*)(bq + (rb + 48) * 32 + cofs);                   \
    }                                                                         \
    STAGE;                                                                    \
    __builtin_amdgcn_s_barrier();                                             \
    asm volatile("s_waitcnt lgkmcnt(0)" ::: "memory");                        \
    __builtin_amdgcn_sched_barrier(0);                                        \
    __builtin_amdgcn_s_setprio(1);                                            \
    _Pragma("unroll")                                                         \
    for (int f_ = 0; f_ < 4; ++f_)                                            \
      _Pragma("unroll")                                                       \
      for (int j_ = 0; j_ < 4; ++j_)                                          \
        acc[(MH) * 4 + f_][j_] = __builtin_amdgcn_mfma_f32_16x16x32_f16(      \
            afr[f_], bfr[j_], acc[(MH) * 4 + f_][j_], 0, 0, 0);               \
    __builtin_amdgcn_s_setprio(0);                                            \
    __builtin_amdgcn_sched_barrier(0);                                        \
    WAITC;                                                                    \
    __builtin_amdgcn_s_barrier();                                             \
  }

template <typename OutT, int NT, bool NFAST>
__global__ __launch_bounds__(512, 2)
void gemm8p_pers(const f16* __restrict__ A, const f16* __restrict__ B,
                 OutT* __restrict__ C, int N, int K, int lda, int ldc) {
    __shared__ f16 lds[2][2][2][8192];   // [buf][A/B][kh][quarter] = 128 KiB

    int nTn = N >> 8;
    unsigned grid = gridDim.x;
    unsigned cpx = (grid * (unsigned)NT) >> 3;   // XCD chunk size (bijective)

    int tid = threadIdx.x;
    int wave = tid >> 6;
    int lane = tid & 63;
    int wm = wave >> 2;                   // 0..1
    int wn = wave & 3;                    // 0..3
    int lr = lane & 15;
    int cg = lane >> 4;                   // chunk group 0..3
    int cofs = ((cg ^ ((lr >> 1) & 3)) << 3);   // swizzled chunk offset (halfs)

    f32x4 acc[8][4];
#pragma unroll
    for (int i = 0; i < 8; ++i)
#pragma unroll
        for (int j = 0; j < 4; ++j) acc[i][j] = (f32x4){0.f, 0.f, 0.f, 0.f};
    half8 bfr[4];

    // tile j -> (bm,bn): XCD-chunked; map per NFAST
    auto tileMN = [&](int j, int& tm, int& tn) {
        unsigned o = blockIdx.x + grid * (unsigned)j;
        unsigned s = (o & 7u) * cpx + (o >> 3);
        if (NFAST) {
            tm = (int)(s / (unsigned)nTn) * 256;
            tn = (int)(s % (unsigned)nTn) * 256;
        } else {
            unsigned gnn = (unsigned)(4 * nTn);
            unsigned g = s / gnn;
            unsigned r = s - g * gnn;
            tm = (int)(g * 4 + (r & 3u)) * 256;
            tn = (int)(r >> 2) * 256;
        }
    };

    int bm, bn;
    tileMN(0, bm, bn);

    // prologue: kt0 fully (8 loads), kt1 B0/A0/B1 (6 loads); kt1 A1 at ph1
    stage_q(B, K,   bn, 0,  &lds[0][1][0][0], tid, wave);
    stage_q(A, lda, bm, 0,  &lds[0][0][0][0], tid, wave);
    stage_q(B, K,   bn, 32, &lds[0][1][1][0], tid, wave);
    stage_q(A, lda, bm, 32, &lds[0][0][1][0], tid, wave);
    stage_q(B, K,   bn, 64, &lds[1][1][0][0], tid, wave);
    stage_q(A, lda, bm, 64, &lds[1][0][0][0], tid, wave);
    stage_q(B, K,   bn, 96, &lds[1][1][1][0], tid, wave);
    asm volatile("s_waitcnt vmcnt(6)" ::: "memory");
    __builtin_amdgcn_s_barrier();

    int NI = K >> 7;                      // 2 K-tiles per iteration
    for (int j = 0; j < NT; ++j) {
        int bm2 = bm, bn2 = bn;
        if (j + 1 < NT) tileMN(j + 1, bm2, bn2);

        for (int it = 0; it < NI; ++it) {
            int gk = it << 7;
            bool lastIter = (it == NI - 1);
            bool fin = lastIter && (j + 1 == NT);   // absolute end
            int sbm = lastIter ? bm2 : bm;
            int sbn = lastIter ? bn2 : bn;
            int sgk = lastIter ? 0 : gk + 128;

            // --- K-tile kt0 (buf 0) ---
            PH(0, 0, 0, true,
               { stage_q(A, lda, bm, gk + 96, &lds[1][0][1][0], tid, wave); }, {});
            PH(0, 0, 1, false,
               { if (!fin) stage_q(B, K, sbn, sgk, &lds[0][1][0][0], tid, wave); }, {});
            PH(0, 1, 0, true,
               { if (!fin) stage_q(A, lda, sbm, sgk, &lds[0][0][0][0], tid, wave); }, {});
            PH(0, 1, 1, false,
               { if (!fin) stage_q(B, K, sbn, sgk + 32, &lds[0][1][1][0], tid, wave); },
               { if (fin) asm volatile("s_waitcnt vmcnt(0)" ::: "memory");
                 else     asm volatile("s_waitcnt vmcnt(6)" ::: "memory"); });
            // --- K-tile kt1 (buf 1) ---
            PH(1, 0, 0, true,
               { if (!fin) stage_q(A, lda, sbm, sgk + 32, &lds[0][0][1][0], tid, wave); }, {});
            PH(1, 0, 1, false,
               { if (!fin) stage_q(B, K, sbn, sgk + 64, &lds[1][1][0][0], tid, wave); }, {});
            PH(1, 1, 0, true,
               { if (!fin) stage_q(A, lda, sbm, sgk + 64, &lds[1][0][0][0], tid, wave); }, {});
            PH(1, 1, 1, false,
               { if (!fin) stage_q(B, K, sbn, sgk + 96, &lds[1][1][1][0], tid, wave); },
               { if (!fin) asm volatile("s_waitcnt vmcnt(6)" ::: "memory"); });
        }

        // epilogue tile j (registers only; no LDS -> safe vs in-flight stages)
        int orow0 = bm + wm * 128 + (lane >> 4) * 4;
        int ocol0 = bn + wn * 64 + lr;
#pragma unroll
        for (int mf = 0; mf < 8; ++mf)
#pragma unroll
            for (int nj = 0; nj < 4; ++nj)
#pragma unroll
                for (int r = 0; r < 4; ++r)
                    C[(size_t)(orow0 + mf * 16 + r) * ldc + (ocol0 + nj * 16)] =
                        (OutT)acc[mf][nj][r];
#pragma unroll
        for (int i2 = 0; i2 < 8; ++i2)
#pragma unroll
            for (int j2 = 0; j2 < 4; ++j2) acc[i2][j2] = (f32x4){0.f, 0.f, 0.f, 0.f};
        bm = bm2; bn = bn2;
    }
}

// ---------------------------------------------------------------------------
// x_dbl = x_conv @ Wh^T  (M=16384, N=48 padded from 33, K=2048) via MFMA.
// ---------------------------------------------------------------------------
__global__ __launch_bounds__(256, 2)
void xdbl_mfma_k(const f16* __restrict__ xc, const f16* __restrict__ Wh,
                 float* __restrict__ xdbl) {
    __shared__ f16 As[64 * 64];   // 8 KB
    __shared__ f16 Bs[48 * 64];   // 6 KB
    int bm = blockIdx.x * 64;
    int tid = threadIdx.x;
    int wave = tid >> 6;
    int lane = tid & 63;
    int srow = lane >> 3;
    int scol = (lane & 7) * 8;
    int lr = lane & 15;
    int lkh = (lane >> 4) * 8;

    f32x4 acc[3];
#pragma unroll
    for (int j = 0; j < 3; ++j) acc[j] = (f32x4){0.f, 0.f, 0.f, 0.f};

    for (int k0 = 0; k0 < 2048; k0 += 64) {
        __syncthreads();
#pragma unroll
        for (int i = 0; i < 2; ++i) {
            int slot = wave * 2 + i;
            gload_lds16(xc + (size_t)(bm + slot * 8 + srow) * 2048 + (k0 + scol),
                        As + slot * 512);
        }
        if (wave < 3) {
#pragma unroll
            for (int i = 0; i < 2; ++i) {
                int slot = wave * 2 + i;
                gload_lds16(Wh + (size_t)(slot * 8 + srow) * 2048 + (k0 + scol),
                            Bs + slot * 512);
            }
        }
        asm volatile("s_waitcnt vmcnt(0)" ::: "memory");
        __syncthreads();
#pragma unroll
        for (int kk = 0; kk < 2; ++kk) {
            half8 a = *(const half8*)(As + (wave * 16 + lr) * 64 + kk * 32 + lkh);
#pragma unroll
            for (int nj = 0; nj < 3; ++nj) {
                half8 b = *(const half8*)(Bs + (nj * 16 + lr) * 64 + kk * 32 + lkh);
                acc[nj] = __builtin_amdgcn_mfma_f32_16x16x32_f16(a, b, acc[nj], 0, 0, 0);
            }
        }
    }

    int orow0 = bm + wave * 16 + (lane >> 4) * 4;
#pragma unroll
    for (int nj = 0; nj < 3; ++nj) {
        int col = nj * 16 + lr;
        if (col < 33) {
#pragma unroll
            for (int r = 0; r < 4; ++r)
                xdbl[(size_t)(orow0 + r) * 33 + col] = acc[nj][r];
        }
    }
}

// ---------------------------------------------------------------------------
// Depthwise causal conv (k=4) + bias + SiLU.  16 rows/block (grid 1024),
// sliding 19-row register window.
// ---------------------------------------------------------------------------
__global__ __launch_bounds__(256)
void conv_silu_k(const f16* __restrict__ xz, const float* __restrict__ cw,
                 const float* __restrict__ cb, f16* __restrict__ xc) {
    int r0 = blockIdx.x * 16;    // first output row (0..16368)
    int d0 = threadIdx.x << 3;   // 0..2040
    int l0 = r0 & 4095;          // position within batch

    const float4* cw4 = (const float4*)cw;
    float4 w[8];
    float bias[8];
#pragma unroll
    for (int e = 0; e < 8; ++e) { w[e] = cw4[d0 + e]; bias[e] = cb[d0 + e]; }

    half8 xv[19];
#pragma unroll
    for (int j = 0; j < 19; ++j) {
        if (l0 - 3 + j >= 0)
            xv[j] = *(const half8*)(xz + (size_t)(r0 - 3 + j) * 4096 + d0);
        else
            xv[j] = (half8){};
    }

#pragma unroll
    for (int rr = 0; rr < 16; ++rr) {
        float acc[8];
#pragma unroll
        for (int e = 0; e < 8; ++e) acc[e] = bias[e];
#pragma unroll
        for (int k = 0; k < 4; ++k) {
            half8 xk = xv[rr + k];
#pragma unroll
            for (int e = 0; e < 8; ++e) {
                float wj = (k == 0) ? w[e].x : (k == 1) ? w[e].y : (k == 2) ? w[e].z : w[e].w;
                acc[e] = fmaf((float)xk[e], wj, acc[e]);
            }
        }
        half8 out = {};
#pragma unroll
        for (int e = 0; e < 8; ++e) {
            float v = acc[e];
            out[e] = (f16)(v / (1.f + expf(-v)));
        }
        *(half8*)(xc + (size_t)(r0 + rr) * 2048 + d0) = out;
    }
}

// ---------------------------------------------------------------------------
// In-LDS SP build shared by scan1/scan2 (T=128):
// sp[t][48] = { exp(A_n*delta_t), delta_t*B_t, C_t } built from xdbl chunk.
// ---------------------------------------------------------------------------
__device__ __forceinline__ void build_sp(const float* __restrict__ xdbl,
                                         const float* __restrict__ alog,
                                         float* sp, float* red,
                                         int bc, int tid) {
    if (tid < 128) {
        int m = bc * 128 + tid;
        const float* row = xdbl + (size_t)m * 33;
        float v0 = row[0];
        float d = (v0 > 15.f) ? v0 : logf(1.f + expf(v0));  // softplus
        float* s = sp + tid * 48;
#pragma unroll
        for (int n = 0; n < 16; ++n) {
            float An = -expf(alog[n]);
            s[n] = expf(An * d);
            s[16 + n] = d * row[1 + n];
            s[32 + n] = row[17 + n];
        }
        if (red) red[tid] = d;
    }
}

// ---------------------------------------------------------------------------
// Scan pass 1 (T=128, 4 d-columns/thread): SP in LDS; h0=0 -> F (f16);
// dg==0 writes G.  Grid 256 = 128 chunks x 2 dgs of 1024 d each.
// LDS broadcasts amortized over 4 chains; x loads are half4 (8B/lane).
// ---------------------------------------------------------------------------
__global__ __launch_bounds__(256)
void scan1_k(const f16* __restrict__ xc, const float* __restrict__ xdbl,
             const float* __restrict__ A_log,
             f16* __restrict__ F, float* __restrict__ G) {
    __shared__ float sp[128 * 48];
    __shared__ float red[128];
    __shared__ float alog[16];
    int blk = blockIdx.x;
    int dg = blk & 1;
    int bc = blk >> 1;               // chunk 0..127
    int tid = threadIdx.x;
    int d0 = dg * 1024 + tid * 4;
    int mbase = bc * 128;

    if (tid < 16) alog[tid] = A_log[tid];
    __syncthreads();
    build_sp(xdbl, alog, sp, red, bc, tid);
    __syncthreads();
#pragma unroll
    for (int s2 = 64; s2 > 0; s2 >>= 1) {
        if (tid < s2) red[tid] += red[tid + s2];
        __syncthreads();
    }
    if (dg == 0 && tid < 16)
        G[bc * 16 + tid] = expf(-expf(alog[tid]) * red[0]);

    float h[4][16];
#pragma unroll
    for (int c = 0; c < 4; ++c)
#pragma unroll
        for (int n = 0; n < 16; ++n) h[c][n] = 0.f;

    for (int tt = 0; tt < 128; ++tt) {
        const float* r = sp + tt * 48;
        half4v xv = *(const half4v*)(xc + (size_t)(mbase + tt) * 2048 + d0);
        float xf[4];
#pragma unroll
        for (int c = 0; c < 4; ++c) xf[c] = (float)xv[c];
#pragma unroll
        for (int n = 0; n < 16; ++n) {
            float dA = r[n], dB = r[16 + n];
#pragma unroll
            for (int c = 0; c < 4; ++c)
                h[c][n] = fmaf(h[c][n], dA, xf[c] * dB);
        }
    }
    size_t fb = ((size_t)bc * 2048 + d0) * 16;   // 64 contiguous f16
#pragma unroll
    for (int c = 0; c < 4; ++c) {
        half8 o0, o1;
#pragma unroll
        for (int n = 0; n < 8; ++n) { o0[n] = (f16)h[c][n]; o1[n] = (f16)h[c][8 + n]; }
        *(half8*)(F + fb + c * 16) = o0;
        *(half8*)(F + fb + c * 16 + 8) = o1;
    }
}

// ---------------------------------------------------------------------------
// Combine: one thread per (b,d,n) scalar chain (131072 chains, 32 steps).
// ---------------------------------------------------------------------------
__global__ __launch_bounds__(256)
void combine_k(const f16* __restrict__ F, const float* __restrict__ G,
               f16* __restrict__ H0) {
    int gid = blockIdx.x * 256 + threadIdx.x;  // 0..131071
    int b = gid >> 15;
    int dn = gid & 32767;
    int n = dn & 15;
    float h = 0.f;
    for (int c = 0; c < 32; ++c) {
        int bc = b * 32 + c;
        size_t idx = (size_t)bc * 32768 + dn;
        H0[idx] = (f16)h;
        h = fmaf(G[bc * 16 + n], h, (float)F[idx]);
    }
}

// ---------------------------------------------------------------------------
// Scan pass 2 (T=128, 4 d-columns/thread): SP in LDS; replay with h0 (f16);
// emit y = (scan_y + x*D) * silu(z).  Grid 256.
// ---------------------------------------------------------------------------
__global__ __launch_bounds__(256)
void scan2_k(const f16* __restrict__ xc, const f16* xz,
             const float* __restrict__ xdbl, const float* __restrict__ A_log,
             const f16* __restrict__ H0, const float* __restrict__ Dv,
             f16* yout) {
    __shared__ float sp[128 * 48];
    __shared__ float alog[16];
    int blk = blockIdx.x;
    int dg = blk & 1;
    int bc = blk >> 1;
    int tid = threadIdx.x;
    int d0 = dg * 1024 + tid * 4;
    int mbase = bc * 128;

    // issue state loads early (independent of LDS)
    size_t fb = ((size_t)bc * 2048 + d0) * 16;   // 64 contiguous f16
    half8 v[8];
#pragma unroll
    for (int q = 0; q < 8; ++q) v[q] = *(const half8*)(H0 + fb + q * 8);
    float Dd[4];
#pragma unroll
    for (int c = 0; c < 4; ++c) Dd[c] = Dv[d0 + c];

    if (tid < 16) alog[tid] = A_log[tid];
    __syncthreads();
    build_sp(xdbl, alog, sp, nullptr, bc, tid);
    __syncthreads();

    float h[4][16];
#pragma unroll
    for (int c = 0; c < 4; ++c)
#pragma unroll
        for (int n = 0; n < 16; ++n)
            h[c][n] = (float)v[c * 2 + (n >> 3)][n & 7];

    for (int tt = 0; tt < 128; ++tt) {
        const float* r = sp + tt * 48;
        size_t mrow = (size_t)(mbase + tt);
        half4v xv = *(const half4v*)(xc + mrow * 2048 + d0);
        half4v zv = *(const half4v*)(xz + mrow * 4096 + 2048 + d0);
        float xf[4], y0[4], y1[4];
#pragma unroll
        for (int c = 0; c < 4; ++c) { xf[c] = (float)xv[c]; y0[c] = 0.f; y1[c] = 0.f; }
#pragma unroll
        for (int n = 0; n < 16; n += 2) {
            float dA0 = r[n], dA1 = r[n + 1];
            float dB0 = r[16 + n], dB1 = r[17 + n];
            float c0 = r[32 + n], c1 = r[33 + n];
#pragma unroll
            for (int c = 0; c < 4; ++c) {
                h[c][n]     = fmaf(h[c][n],     dA0, xf[c] * dB0);
                h[c][n + 1] = fmaf(h[c][n + 1], dA1, xf[c] * dB1);
                y0[c] = fmaf(h[c][n],     c0, y0[c]);
                y1[c] = fmaf(h[c][n + 1], c1, y1[c]);
            }
        }
        half4v o;
#pragma unroll
        for (int c = 0; c < 4; ++c) {
            float zc = (float)zv[c];
            float yf = fmaf(xf[c], Dd[c], y0[c] + y1[c]);
            float sz = zc / (1.f + expf(-zc));
            o[c] = (f16)(yf * sz);
        }
        *(half4v*)(yout + mrow * 4096 + d0) = o;
    }
}

// ---------------------------------------------------------------------------
// Workspace layout (aliased by lifetime; peak 224,665,600 B ~= 214 MiB):
//   [0,   134217728)  xzh  : f16 16384x4096 (x_inner|z; x_inner cols become y)
//   [134217728, +67108864) region1:
//        phase A (prep+GEMM1):  xh f16 16384x1024 @ +0, wih f16 4096x1024 @ +33554432
//        phase B (conv..scan2): xch f16 16384x2048 @ +0
//   [201326592, ...)  xdbl(2162688) G(8192) F_f16(8388608) H0_f16(8388608)
//                     Wh(196608) woh(4194304)   end = 224665600
// ---------------------------------------------------------------------------
extern "C" void kernel_launch(void* const* d_in, const int* in_sizes, int n_in,
                              void* d_out, int out_size, void* d_ws, size_t ws_size,
                              hipStream_t stream) {
    const float* x      = (const float*)d_in[0];
    const float* w_in   = (const float*)d_in[1];
    const float* conv_w = (const float*)d_in[2];
    const float* conv_b = (const float*)d_in[3];
    const float* w_xp   = (const float*)d_in[4];
    const float* A_log  = (const float*)d_in[5];
    const float* Dv     = (const float*)d_in[6];
    const float* w_out  = (const float*)d_in[7];

    char* base = (char*)d_ws;
    f16* xzh = (f16*)base;                          // 134217728 B
    char* r1 = base + 134217728;                    // 67108864 B shared region
    f16* xh  = (f16*)r1;                            // 33554432 B   (phase A)
    f16* wih = (f16*)(r1 + 33554432);               // 8388608 B    (phase A)
    f16* xch = (f16*)r1;                            // 67108864 B   (phase B)
    char* p = base + 201326592;
    float* xdbl = (float*)p;  p += 2162688;         // 16384x33
    float* G    = (float*)p;  p += 8192;            // 128x16
    f16*   F    = (f16*)p;    p += 8388608;         // 128x2048x16 f16
    f16*   H0   = (f16*)p;    p += 8388608;         // 128x2048x16 f16
    f16*   Wh   = (f16*)p;    p += 196608;          // 48x2048 f16 padded x_proj_w
    f16*   woh  = (f16*)p;    p += 4194304;         // 1024x2048 f16 out_proj_w

    // fused dtype conversions (x, in_proj_w, padded x_proj_w, out_proj_w)
    prep_k<<<3456, 256, 0, stream>>>(x, w_in, w_xp, w_out, xh, wih, Wh, woh);

    // xz = x @ in_proj_w^T  (M=16384, N=4096, K=1024) — persistent, 4 tiles/blk
    gemm8p_pers<f16, 4, false><<<256, 512, 0, stream>>>(xh, wih, xzh,
                                                        4096, 1024, 1024, 4096);

    // depthwise conv + SiLU -> x_conv   (xh/wih dead; xch overlays them)
    conv_silu_k<<<1024, 256, 0, stream>>>(xzh, conv_w, conv_b, xch);

    // x_dbl = x_conv @ x_proj_w^T  (N=33 padded to 48) via MFMA
    xdbl_mfma_k<<<256, 256, 0, stream>>>(xch, Wh, xdbl);

    // chunked selective scan (T=128, 32 chunks/batch; 4 d/thread)
    scan1_k<<<256, 256, 0, stream>>>(xch, xdbl, A_log, F, G);
    combine_k<<<512, 256, 0, stream>>>(F, G, H0);
    scan2_k<<<256, 256, 0, stream>>>(xch, xzh, xdbl, A_log, H0, Dv, xzh);

    // out = y @ out_proj_w^T  (M=16384, N=1024, K=2048) — N-fast tile map
    gemm8p_pers<float, 1, true><<<256, 512, 0, stream>>>(xzh, woh, (float*)d_out,
                                                         1024, 2048, 4096, 1024);
}

// Round 17
// 417.868 us; speedup vs baseline: 1.1635x; 1.1635x over previous
//
#include <hip/hip_runtime.h>
#include <hip/hip_fp16.h>

typedef _Float16 f16;
typedef _Float16 half8 __attribute__((ext_vector_type(8)));
typedef _Float16 half4v __attribute__((ext_vector_type(4)));
typedef _Float16 half2v __attribute__((ext_vector_type(2)));
typedef float f32x4 __attribute__((ext_vector_type(4)));

#define AS1(p) ((const __attribute__((address_space(1))) void*)(p))
#define AS3(p) ((__attribute__((address_space(3))) void*)(p))

__device__ __forceinline__ void gload_lds16(const void* g, void* l) {
    __builtin_amdgcn_global_load_lds(AS1(g), AS3(l), 16, 0, 0);
}

// ---------------------------------------------------------------------------
// Fused input conversions: x, in_proj_w, out_proj_w (f32->f16) and
// x_proj_w (33x2048 -> zero-padded 48x2048 f16).  Grid 3456.
// ---------------------------------------------------------------------------
__global__ __launch_bounds__(256)
void prep_k(const float* __restrict__ x, const float* __restrict__ w_in,
            const float* __restrict__ w_xp, const float* __restrict__ w_out,
            f16* __restrict__ xh, f16* __restrict__ wih,
            f16* __restrict__ Wh, f16* __restrict__ woh) {
    int b = blockIdx.x;
    if (b < 2048) {
        for (int i = b * 256 + threadIdx.x; i < 4194304; i += 2048 * 256) {
            float4 v = ((const float4*)x)[i];
            half4v o; o[0] = (f16)v.x; o[1] = (f16)v.y; o[2] = (f16)v.z; o[3] = (f16)v.w;
            ((half4v*)xh)[i] = o;
        }
    } else if (b < 2560) {
        for (int i = (b - 2048) * 256 + threadIdx.x; i < 1048576; i += 512 * 256) {
            float4 v = ((const float4*)w_in)[i];
            half4v o; o[0] = (f16)v.x; o[1] = (f16)v.y; o[2] = (f16)v.z; o[3] = (f16)v.w;
            ((half4v*)wih)[i] = o;
        }
    } else if (b < 2944) {
        int idx = (b - 2560) * 256 + threadIdx.x;   // 0..98303
        int e = idx >> 11;
        int k = idx & 2047;
        Wh[idx] = (e < 33) ? (f16)w_xp[e * 2048 + k] : (f16)0.f;
    } else {
        for (int i = (b - 2944) * 256 + threadIdx.x; i < 524288; i += 512 * 256) {
            float4 v = ((const float4*)w_out)[i];
            half4v o; o[0] = (f16)v.x; o[1] = (f16)v.y; o[2] = (f16)v.z; o[3] = (f16)v.w;
            ((half4v*)woh)[i] = o;
        }
    }
}

// ===========================================================================
// Persistent 256x256 8-phase GEMM (proven variant), f16 MFMA 16x16x32.
// NFAST=false: 4x8 supertile (GEMM1).  NFAST=true: bn-fastest (GEMM2).
// Bridged prologue + vmcnt(6) pipeline.
// ===========================================================================
__device__ __forceinline__ void stage_q(const f16* __restrict__ g, int ld,
                                        int row0, int gk, f16* q,
                                        int tid, int wave) {
#pragma unroll
    for (int rd = 0; rd < 2; ++rd) {
        int t = rd * 512 + tid;
        int r = t >> 2;                       // row 0..255
        int cu = (t & 3) ^ ((r >> 1) & 3);    // unswizzled chunk for this slot
        gload_lds16(g + (size_t)(row0 + r) * ld + gk + cu * 8,
                    q + rd * 4096 + wave * 512);   // wave-uniform linear dest
    }
}

#define PH(Q, KH, MH, LOADB, STAGE, WAITC)                                    \
  {                                                                           \
    half8 afr[4];                                                             \
    {                                                                         \
      const f16* aq = &lds[Q][0][KH][0];                                      \
      int ra = wm * 128 + (MH) * 64 + lr;                                     \
      afr[0] = *(const half8*)(aq + (ra +  0) * 32 + cofs);                   \
      afr[1] = *(const half8*)(aq + (ra + 16) * 32 + cofs);                   \
      afr[2] = *(const half8*)(aq + (ra + 32) * 32 + cofs);                   \
      afr[3] = *(const half8*)(aq + (ra + 48) * 32 + cofs);                   \
    }                                                                         \
    if (LOADB) {                                                              \
      const f16* bq = &lds[Q][1][KH][0];                                      \
      int rb = wn * 64 + lr;                                                  \
      bfr[0] = *(const half8*)(bq + (rb +  0) * 32 + cofs);                   \
      bfr[1] = *(const half8*)(bq + (rb + 16) * 32 + cofs);                   \
      bfr[2] = *(const half8*)(bq + (rb + 32) * 32 + cofs);                   \
      bfr[3] = *(const half8*)(bq + (rb + 48) * 32 + cofs);                   \
    }                                                                         \
    STAGE;                                                                    \
    __builtin_amdgcn_s_barrier();                                             \
    asm volatile("s_waitcnt lgkmcnt(0)" ::: "memory");                        \
    __builtin_amdgcn_sched_barrier(0);                                        \
    __builtin_amdgcn_s_setprio(1);                                            \
    _Pragma("unroll")                                                         \
    for (int f_ = 0; f_ < 4; ++f_)                                            \
      _Pragma("unroll")                                                       \
      for (int j_ = 0; j_ < 4; ++j_)                                          \
        acc[(MH) * 4 + f_][j_] = __builtin_amdgcn_mfma_f32_16x16x32_f16(      \
            afr[f_], bfr[j_], acc[(MH) * 4 + f_][j_], 0, 0, 0);               \
    __builtin_amdgcn_s_setprio(0);                                            \
    __builtin_amdgcn_sched_barrier(0);                                        \
    WAITC;                                                                    \
    __builtin_amdgcn_s_barrier();                                             \
  }

template <typename OutT, int NT, bool NFAST>
__global__ __launch_bounds__(512, 2)
void gemm8p_pers(const f16* __restrict__ A, const f16* __restrict__ B,
                 OutT* __restrict__ C, int N, int K, int lda, int ldc) {
    __shared__ f16 lds[2][2][2][8192];   // [buf][A/B][kh][quarter] = 128 KiB

    int nTn = N >> 8;
    unsigned grid = gridDim.x;
    unsigned cpx = (grid * (unsigned)NT) >> 3;   // XCD chunk size (bijective)

    int tid = threadIdx.x;
    int wave = tid >> 6;
    int lane = tid & 63;
    int wm = wave >> 2;                   // 0..1
    int wn = wave & 3;                    // 0..3
    int lr = lane & 15;
    int cg = lane >> 4;                   // chunk group 0..3
    int cofs = ((cg ^ ((lr >> 1) & 3)) << 3);   // swizzled chunk offset (halfs)

    f32x4 acc[8][4];
#pragma unroll
    for (int i = 0; i < 8; ++i)
#pragma unroll
        for (int j = 0; j < 4; ++j) acc[i][j] = (f32x4){0.f, 0.f, 0.f, 0.f};
    half8 bfr[4];

    // tile j -> (bm,bn): XCD-chunked; map per NFAST
    auto tileMN = [&](int j, int& tm, int& tn) {
        unsigned o = blockIdx.x + grid * (unsigned)j;
        unsigned s = (o & 7u) * cpx + (o >> 3);
        if (NFAST) {
            tm = (int)(s / (unsigned)nTn) * 256;
            tn = (int)(s % (unsigned)nTn) * 256;
        } else {
            unsigned gnn = (unsigned)(4 * nTn);
            unsigned g = s / gnn;
            unsigned r = s - g * gnn;
            tm = (int)(g * 4 + (r & 3u)) * 256;
            tn = (int)(r >> 2) * 256;
        }
    };

    int bm, bn;
    tileMN(0, bm, bn);

    // prologue: kt0 fully (8 loads), kt1 B0/A0/B1 (6 loads); kt1 A1 at ph1
    stage_q(B, K,   bn, 0,  &lds[0][1][0][0], tid, wave);
    stage_q(A, lda, bm, 0,  &lds[0][0][0][0], tid, wave);
    stage_q(B, K,   bn, 32, &lds[0][1][1][0], tid, wave);
    stage_q(A, lda, bm, 32, &lds[0][0][1][0], tid, wave);
    stage_q(B, K,   bn, 64, &lds[1][1][0][0], tid, wave);
    stage_q(A, lda, bm, 64, &lds[1][0][0][0], tid, wave);
    stage_q(B, K,   bn, 96, &lds[1][1][1][0], tid, wave);
    asm volatile("s_waitcnt vmcnt(6)" ::: "memory");
    __builtin_amdgcn_s_barrier();

    int NI = K >> 7;                      // 2 K-tiles per iteration
    for (int j = 0; j < NT; ++j) {
        int bm2 = bm, bn2 = bn;
        if (j + 1 < NT) tileMN(j + 1, bm2, bn2);

        for (int it = 0; it < NI; ++it) {
            int gk = it << 7;
            bool lastIter = (it == NI - 1);
            bool fin = lastIter && (j + 1 == NT);   // absolute end
            int sbm = lastIter ? bm2 : bm;
            int sbn = lastIter ? bn2 : bn;
            int sgk = lastIter ? 0 : gk + 128;

            // --- K-tile kt0 (buf 0) ---
            PH(0, 0, 0, true,
               { stage_q(A, lda, bm, gk + 96, &lds[1][0][1][0], tid, wave); }, {});
            PH(0, 0, 1, false,
               { if (!fin) stage_q(B, K, sbn, sgk, &lds[0][1][0][0], tid, wave); }, {});
            PH(0, 1, 0, true,
               { if (!fin) stage_q(A, lda, sbm, sgk, &lds[0][0][0][0], tid, wave); }, {});
            PH(0, 1, 1, false,
               { if (!fin) stage_q(B, K, sbn, sgk + 32, &lds[0][1][1][0], tid, wave); },
               { if (fin) asm volatile("s_waitcnt vmcnt(0)" ::: "memory");
                 else     asm volatile("s_waitcnt vmcnt(6)" ::: "memory"); });
            // --- K-tile kt1 (buf 1) ---
            PH(1, 0, 0, true,
               { if (!fin) stage_q(A, lda, sbm, sgk + 32, &lds[0][0][1][0], tid, wave); }, {});
            PH(1, 0, 1, false,
               { if (!fin) stage_q(B, K, sbn, sgk + 64, &lds[1][1][0][0], tid, wave); }, {});
            PH(1, 1, 0, true,
               { if (!fin) stage_q(A, lda, sbm, sgk + 64, &lds[1][0][0][0], tid, wave); }, {});
            PH(1, 1, 1, false,
               { if (!fin) stage_q(B, K, sbn, sgk + 96, &lds[1][1][1][0], tid, wave); },
               { if (!fin) asm volatile("s_waitcnt vmcnt(6)" ::: "memory"); });
        }

        // epilogue tile j (registers only; no LDS -> safe vs in-flight stages)
        int orow0 = bm + wm * 128 + (lane >> 4) * 4;
        int ocol0 = bn + wn * 64 + lr;
#pragma unroll
        for (int mf = 0; mf < 8; ++mf)
#pragma unroll
            for (int nj = 0; nj < 4; ++nj)
#pragma unroll
                for (int r = 0; r < 4; ++r)
                    C[(size_t)(orow0 + mf * 16 + r) * ldc + (ocol0 + nj * 16)] =
                        (OutT)acc[mf][nj][r];
#pragma unroll
        for (int i2 = 0; i2 < 8; ++i2)
#pragma unroll
            for (int j2 = 0; j2 < 4; ++j2) acc[i2][j2] = (f32x4){0.f, 0.f, 0.f, 0.f};
        bm = bm2; bn = bn2;
    }
}

// ---------------------------------------------------------------------------
// x_dbl = x_conv @ Wh^T  (M=16384, N=48 padded from 33, K=2048) via MFMA.
// ---------------------------------------------------------------------------
__global__ __launch_bounds__(256, 2)
void xdbl_mfma_k(const f16* __restrict__ xc, const f16* __restrict__ Wh,
                 float* __restrict__ xdbl) {
    __shared__ f16 As[64 * 64];   // 8 KB
    __shared__ f16 Bs[48 * 64];   // 6 KB
    int bm = blockIdx.x * 64;
    int tid = threadIdx.x;
    int wave = tid >> 6;
    int lane = tid & 63;
    int srow = lane >> 3;
    int scol = (lane & 7) * 8;
    int lr = lane & 15;
    int lkh = (lane >> 4) * 8;

    f32x4 acc[3];
#pragma unroll
    for (int j = 0; j < 3; ++j) acc[j] = (f32x4){0.f, 0.f, 0.f, 0.f};

    for (int k0 = 0; k0 < 2048; k0 += 64) {
        __syncthreads();
#pragma unroll
        for (int i = 0; i < 2; ++i) {
            int slot = wave * 2 + i;
            gload_lds16(xc + (size_t)(bm + slot * 8 + srow) * 2048 + (k0 + scol),
                        As + slot * 512);
        }
        if (wave < 3) {
#pragma unroll
            for (int i = 0; i < 2; ++i) {
                int slot = wave * 2 + i;
                gload_lds16(Wh + (size_t)(slot * 8 + srow) * 2048 + (k0 + scol),
                            Bs + slot * 512);
            }
        }
        asm volatile("s_waitcnt vmcnt(0)" ::: "memory");
        __syncthreads();
#pragma unroll
        for (int kk = 0; kk < 2; ++kk) {
            half8 a = *(const half8*)(As + (wave * 16 + lr) * 64 + kk * 32 + lkh);
#pragma unroll
            for (int nj = 0; nj < 3; ++nj) {
                half8 b = *(const half8*)(Bs + (nj * 16 + lr) * 64 + kk * 32 + lkh);
                acc[nj] = __builtin_amdgcn_mfma_f32_16x16x32_f16(a, b, acc[nj], 0, 0, 0);
            }
        }
    }

    int orow0 = bm + wave * 16 + (lane >> 4) * 4;
#pragma unroll
    for (int nj = 0; nj < 3; ++nj) {
        int col = nj * 16 + lr;
        if (col < 33) {
#pragma unroll
            for (int r = 0; r < 4; ++r)
                xdbl[(size_t)(orow0 + r) * 33 + col] = acc[nj][r];
        }
    }
}

// ---------------------------------------------------------------------------
// Depthwise causal conv (k=4) + bias + SiLU.  16 rows/block (grid 1024),
// sliding 19-row register window.
// ---------------------------------------------------------------------------
__global__ __launch_bounds__(256)
void conv_silu_k(const f16* __restrict__ xz, const float* __restrict__ cw,
                 const float* __restrict__ cb, f16* __restrict__ xc) {
    int r0 = blockIdx.x * 16;    // first output row (0..16368)
    int d0 = threadIdx.x << 3;   // 0..2040
    int l0 = r0 & 4095;          // position within batch

    const float4* cw4 = (const float4*)cw;
    float4 w[8];
    float bias[8];
#pragma unroll
    for (int e = 0; e < 8; ++e) { w[e] = cw4[d0 + e]; bias[e] = cb[d0 + e]; }

    half8 xv[19];
#pragma unroll
    for (int j = 0; j < 19; ++j) {
        if (l0 - 3 + j >= 0)
            xv[j] = *(const half8*)(xz + (size_t)(r0 - 3 + j) * 4096 + d0);
        else
            xv[j] = (half8){};
    }

#pragma unroll
    for (int rr = 0; rr < 16; ++rr) {
        float acc[8];
#pragma unroll
        for (int e = 0; e < 8; ++e) acc[e] = bias[e];
#pragma unroll
        for (int k = 0; k < 4; ++k) {
            half8 xk = xv[rr + k];
#pragma unroll
            for (int e = 0; e < 8; ++e) {
                float wj = (k == 0) ? w[e].x : (k == 1) ? w[e].y : (k == 2) ? w[e].z : w[e].w;
                acc[e] = fmaf((float)xk[e], wj, acc[e]);
            }
        }
        half8 out = {};
#pragma unroll
        for (int e = 0; e < 8; ++e) {
            float v = acc[e];
            out[e] = (f16)(v / (1.f + expf(-v)));
        }
        *(half8*)(xc + (size_t)(r0 + rr) * 2048 + d0) = out;
    }
}

// ---------------------------------------------------------------------------
// In-LDS SP build shared by scan1/scan2 (T=128):
// sp[t][48] = { exp(A_n*delta_t), delta_t*B_t, C_t } built from xdbl chunk.
// ---------------------------------------------------------------------------
__device__ __forceinline__ void build_sp(const float* __restrict__ xdbl,
                                         const float* __restrict__ alog,
                                         float* sp, float* red,
                                         int bc, int tid) {
    if (tid < 128) {
        int m = bc * 128 + tid;
        const float* row = xdbl + (size_t)m * 33;
        float v0 = row[0];
        float d = (v0 > 15.f) ? v0 : logf(1.f + expf(v0));  // softplus
        float* s = sp + tid * 48;
#pragma unroll
        for (int n = 0; n < 16; ++n) {
            float An = -expf(alog[n]);
            s[n] = expf(An * d);
            s[16 + n] = d * row[1 + n];
            s[32 + n] = row[17 + n];
        }
        if (red) red[tid] = d;
    }
}

// ---------------------------------------------------------------------------
// Scan pass 1 (T=128, 2 d-columns/thread): SP in LDS; h0=0 -> F (f16);
// dg==0 writes G.  Grid 512 = 128 chunks x 4 dgs of 512 d each.
// LDS broadcasts amortized over 2 chains; x loads are half2 (4B/lane).
// ---------------------------------------------------------------------------
__global__ __launch_bounds__(256)
void scan1_k(const f16* __restrict__ xc, const float* __restrict__ xdbl,
             const float* __restrict__ A_log,
             f16* __restrict__ F, float* __restrict__ G) {
    __shared__ float sp[128 * 48];
    __shared__ float red[128];
    __shared__ float alog[16];
    int blk = blockIdx.x;
    int dg = blk & 3;
    int bc = blk >> 2;               // chunk 0..127
    int tid = threadIdx.x;
    int d0 = dg * 512 + tid * 2;
    int mbase = bc * 128;

    if (tid < 16) alog[tid] = A_log[tid];
    __syncthreads();
    build_sp(xdbl, alog, sp, red, bc, tid);
    __syncthreads();
#pragma unroll
    for (int s2 = 64; s2 > 0; s2 >>= 1) {
        if (tid < s2) red[tid] += red[tid + s2];
        __syncthreads();
    }
    if (dg == 0 && tid < 16)
        G[bc * 16 + tid] = expf(-expf(alog[tid]) * red[0]);

    float hA[16], hB[16];
#pragma unroll
    for (int n = 0; n < 16; ++n) { hA[n] = 0.f; hB[n] = 0.f; }

    for (int tt = 0; tt < 128; ++tt) {
        const float* r = sp + tt * 48;
        half2v xv = *(const half2v*)(xc + (size_t)(mbase + tt) * 2048 + d0);
        float xa = (float)xv[0], xb = (float)xv[1];
#pragma unroll
        for (int n = 0; n < 16; ++n) {
            float dA = r[n], dB = r[16 + n];
            hA[n] = fmaf(hA[n], dA, xa * dB);
            hB[n] = fmaf(hB[n], dA, xb * dB);
        }
    }
    size_t fb = ((size_t)bc * 2048 + d0) * 16;   // 32 contiguous f16
    half8 o[4];
#pragma unroll
    for (int n = 0; n < 8; ++n) {
        o[0][n] = (f16)hA[n];     o[1][n] = (f16)hA[8 + n];
        o[2][n] = (f16)hB[n];     o[3][n] = (f16)hB[8 + n];
    }
#pragma unroll
    for (int q = 0; q < 4; ++q) *(half8*)(F + fb + q * 8) = o[q];
}

// ---------------------------------------------------------------------------
// Combine: one thread per (b,d,n) scalar chain (131072 chains, 32 steps).
// ---------------------------------------------------------------------------
__global__ __launch_bounds__(256)
void combine_k(const f16* __restrict__ F, const float* __restrict__ G,
               f16* __restrict__ H0) {
    int gid = blockIdx.x * 256 + threadIdx.x;  // 0..131071
    int b = gid >> 15;
    int dn = gid & 32767;
    int n = dn & 15;
    float h = 0.f;
    for (int c = 0; c < 32; ++c) {
        int bc = b * 32 + c;
        size_t idx = (size_t)bc * 32768 + dn;
        H0[idx] = (f16)h;
        h = fmaf(G[bc * 16 + n], h, (float)F[idx]);
    }
}

// ---------------------------------------------------------------------------
// Scan pass 2 (T=128, 2 d-columns/thread): SP in LDS; replay with h0 (f16);
// emit y = (scan_y + x*D) * silu(z).  Grid 512.
// ---------------------------------------------------------------------------
__global__ __launch_bounds__(256)
void scan2_k(const f16* __restrict__ xc, const f16* xz,
             const float* __restrict__ xdbl, const float* __restrict__ A_log,
             const f16* __restrict__ H0, const float* __restrict__ Dv,
             f16* yout) {
    __shared__ float sp[128 * 48];
    __shared__ float alog[16];
    int blk = blockIdx.x;
    int dg = blk & 3;
    int bc = blk >> 2;
    int tid = threadIdx.x;
    int d0 = dg * 512 + tid * 2;
    int mbase = bc * 128;

    // issue state loads early (independent of LDS)
    size_t fb = ((size_t)bc * 2048 + d0) * 16;   // 32 contiguous f16
    half8 v0 = *(const half8*)(H0 + fb);
    half8 v1 = *(const half8*)(H0 + fb + 8);
    half8 v2 = *(const half8*)(H0 + fb + 16);
    half8 v3 = *(const half8*)(H0 + fb + 24);
    float DdA = Dv[d0], DdB = Dv[d0 + 1];

    if (tid < 16) alog[tid] = A_log[tid];
    __syncthreads();
    build_sp(xdbl, alog, sp, nullptr, bc, tid);
    __syncthreads();

    float hA[16], hB[16];
#pragma unroll
    for (int n = 0; n < 8; ++n) {
        hA[n] = (float)v0[n]; hA[8 + n] = (float)v1[n];
        hB[n] = (float)v2[n]; hB[8 + n] = (float)v3[n];
    }

    for (int tt = 0; tt < 128; ++tt) {
        const float* r = sp + tt * 48;
        size_t mrow = (size_t)(mbase + tt);
        half2v xv = *(const half2v*)(xc + mrow * 2048 + d0);
        half2v zv = *(const half2v*)(xz + mrow * 4096 + 2048 + d0);
        float xa = (float)xv[0], xb = (float)xv[1];
        float ya0 = 0.f, ya1 = 0.f, yb0 = 0.f, yb1 = 0.f;
#pragma unroll
        for (int n = 0; n < 16; n += 2) {
            float dA0 = r[n], dA1 = r[n + 1];
            float dB0 = r[16 + n], dB1 = r[17 + n];
            float c0 = r[32 + n], c1 = r[33 + n];
            hA[n]     = fmaf(hA[n],     dA0, xa * dB0);
            hA[n + 1] = fmaf(hA[n + 1], dA1, xa * dB1);
            hB[n]     = fmaf(hB[n],     dA0, xb * dB0);
            hB[n + 1] = fmaf(hB[n + 1], dA1, xb * dB1);
            ya0 = fmaf(hA[n],     c0, ya0);
            ya1 = fmaf(hA[n + 1], c1, ya1);
            yb0 = fmaf(hB[n],     c0, yb0);
            yb1 = fmaf(hB[n + 1], c1, yb1);
        }
        float za = (float)zv[0], zb = (float)zv[1];
        float yfa = fmaf(xa, DdA, ya0 + ya1);
        float yfb = fmaf(xb, DdB, yb0 + yb1);
        float sza = za / (1.f + expf(-za));
        float szb = zb / (1.f + expf(-zb));
        half2v o;
        o[0] = (f16)(yfa * sza);
        o[1] = (f16)(yfb * szb);
        *(half2v*)(yout + mrow * 4096 + d0) = o;
    }
}

// ---------------------------------------------------------------------------
// Workspace layout (aliased by lifetime; peak 224,665,600 B ~= 214 MiB):
//   [0,   134217728)  xzh  : f16 16384x4096 (x_inner|z; x_inner cols become y)
//   [134217728, +67108864) region1:
//        phase A (prep+GEMM1):  xh f16 16384x1024 @ +0, wih f16 4096x1024 @ +33554432
//        phase B (conv..scan2): xch f16 16384x2048 @ +0
//   [201326592, ...)  xdbl(2162688) G(8192) F_f16(8388608) H0_f16(8388608)
//                     Wh(196608) woh(4194304)   end = 224665600
// ---------------------------------------------------------------------------
extern "C" void kernel_launch(void* const* d_in, const int* in_sizes, int n_in,
                              void* d_out, int out_size, void* d_ws, size_t ws_size,
                              hipStream_t stream) {
    const float* x      = (const float*)d_in[0];
    const float* w_in   = (const float*)d_in[1];
    const float* conv_w = (const float*)d_in[2];
    const float* conv_b = (const float*)d_in[3];
    const float* w_xp   = (const float*)d_in[4];
    const float* A_log  = (const float*)d_in[5];
    const float* Dv     = (const float*)d_in[6];
    const float* w_out  = (const float*)d_in[7];

    char* base = (char*)d_ws;
    f16* xzh = (f16*)base;                          // 134217728 B
    char* r1 = base + 134217728;                    // 67108864 B shared region
    f16* xh  = (f16*)r1;                            // 33554432 B   (phase A)
    f16* wih = (f16*)(r1 + 33554432);               // 8388608 B    (phase A)
    f16* xch = (f16*)r1;                            // 67108864 B   (phase B)
    char* p = base + 201326592;
    float* xdbl = (float*)p;  p += 2162688;         // 16384x33
    float* G    = (float*)p;  p += 8192;            // 128x16
    f16*   F    = (f16*)p;    p += 8388608;         // 128x2048x16 f16
    f16*   H0   = (f16*)p;    p += 8388608;         // 128x2048x16 f16
    f16*   Wh   = (f16*)p;    p += 196608;          // 48x2048 f16 padded x_proj_w
    f16*   woh  = (f16*)p;    p += 4194304;         // 1024x2048 f16 out_proj_w

    // fused dtype conversions (x, in_proj_w, padded x_proj_w, out_proj_w)
    prep_k<<<3456, 256, 0, stream>>>(x, w_in, w_xp, w_out, xh, wih, Wh, woh);

    // xz = x @ in_proj_w^T  (M=16384, N=4096, K=1024) — persistent, 4 tiles/blk
    gemm8p_pers<f16, 4, false><<<256, 512, 0, stream>>>(xh, wih, xzh,
                                                        4096, 1024, 1024, 4096);

    // depthwise conv + SiLU -> x_conv   (xh/wih dead; xch overlays them)
    conv_silu_k<<<1024, 256, 0, stream>>>(xzh, conv_w, conv_b, xch);

    // x_dbl = x_conv @ x_proj_w^T  (N=33 padded to 48) via MFMA
    xdbl_mfma_k<<<256, 256, 0, stream>>>(xch, Wh, xdbl);

    // chunked selective scan (T=128, 32 chunks/batch; 2 d/thread)
    scan1_k<<<512, 256, 0, stream>>>(xch, xdbl, A_log, F, G);
    combine_k<<<512, 256, 0, stream>>>(F, G, H0);
    scan2_k<<<512, 256, 0, stream>>>(xch, xzh, xdbl, A_log, H0, Dv, xzh);

    // out = y @ out_proj_w^T  (M=16384, N=1024, K=2048) — N-fast tile map
    gemm8p_pers<float, 1, true><<<256, 512, 0, stream>>>(xzh, woh, (float*)d_out,
                                                         1024, 2048, 4096, 1024);
}